// Round 7
// baseline (618.750 us; speedup 1.0000x reference)
//
#include <hip/hip_runtime.h>

typedef __bf16 bf16x8 __attribute__((ext_vector_type(8)));
typedef float f32x4 __attribute__((ext_vector_type(4)));

__device__ __forceinline__ unsigned short f2bf(float f) {
    union { float f; unsigned u; } v; v.f = f;
    unsigned u = v.u;
    return (unsigned short)((u + 0x7FFFu + ((u >> 16) & 1u)) >> 16);
}
__device__ __forceinline__ float bf2f(unsigned short h) {
    union { unsigned u; float f; } v; v.u = ((unsigned)h) << 16;
    return v.f;
}
__device__ __forceinline__ bf16x8 ld8(const unsigned short* p) {
    union { uint4 u; bf16x8 b; } cv;
    cv.u = *(const uint4*)p;
    return cv.b;
}
__device__ __forceinline__ float sigmoidf_(float x) {
    return __builtin_amdgcn_rcpf(1.0f + __expf(-x));
}
__device__ __forceinline__ float tanhf_(float x) {
    float xc = fminf(fmaxf(x, -15.0f), 15.0f);
    float e = __expf(-2.0f * xc);
    return (1.0f - e) * __builtin_amdgcn_rcpf(1.0f + e);
}

// ---------------- prep: transpose cemb_W, bias sum, W_hh -> bf16 --------------
__global__ void k_prep(const float* __restrict__ cemb_W,
                       const float* __restrict__ b_ih, const float* __restrict__ b_hh,
                       const float* __restrict__ W_hh,
                       float* __restrict__ cWT, float* __restrict__ bsum,
                       unsigned short* __restrict__ Wbf) {
    int i = blockIdx.x * blockDim.x + threadIdx.x;
    int stride = gridDim.x * blockDim.x;
    const int TOT = 32768 + 1024 + 262144;
    for (; i < TOT; i += stride) {
        if (i < 32768) {
            int idx = i >> 8, e = i & 255;
            cWT[idx * 256 + e] = cemb_W[e * 128 + idx];   // cWT[i][e] = cemb_W[e][i]
        } else if (i < 33792) {
            int g = i - 32768;
            bsum[g] = b_ih[g] + b_hh[g];
        } else {
            int j = i - 33792;
            Wbf[j] = f2bf(W_hh[j]);
        }
    }
}

// ---------------- build A_in = [xemb * Cct, onehots] (bf16, rows m = t*128+b) --
__global__ __launch_bounds__(128) void k_build_in(
    const int* __restrict__ c, const int* __restrict__ r,
    const int* __restrict__ rgap, const int* __restrict__ sgap, const int* __restrict__ pcount,
    const float* __restrict__ E, const float* __restrict__ cWT,
    unsigned short* __restrict__ A) {
    int m = blockIdx.x;
    int b = m & 127, t = m >> 7;
    int src = b * 200 + t;
    int x = c[src] + 1024 * r[src];
    int ra = rgap[src], sa = 32 + sgap[src], pa = 64 + pcount[src];
    int e = threadIdx.x;
#pragma unroll
    for (int j = 0; j < 2; ++j) {
        int ee = e + j * 128;
        float cc = cWT[ra * 256 + ee] + cWT[sa * 256 + ee] + cWT[pa * 256 + ee];
        A[(long)m * 384 + ee] = f2bf(E[(long)x * 256 + ee] * cc);
    }
    A[(long)m * 384 + 256 + e] =
        (e == ra || e == sa || e == pa) ? (unsigned short)0x3F80 : (unsigned short)0;
}

// ---------------- build A_out = [h * Cct_shft, onehots] ----------------------
__global__ __launch_bounds__(128) void k_build_out(
    const int* __restrict__ rgap, const int* __restrict__ sgap, const int* __restrict__ pcount,
    const unsigned short* __restrict__ h_all, const float* __restrict__ cWT,
    unsigned short* __restrict__ A) {
    int m = blockIdx.x;
    int b = m & 127, t = m >> 7;
    int src = b * 200 + t;
    int ra = rgap[src], sa = 32 + sgap[src], pa = 64 + pcount[src];
    int e = threadIdx.x;
#pragma unroll
    for (int j = 0; j < 2; ++j) {
        int ee = e + j * 128;
        float cc = cWT[ra * 256 + ee] + cWT[sa * 256 + ee] + cWT[pa * 256 + ee];
        float v = bf2f(h_all[(long)m * 256 + ee]);
        A[(long)m * 384 + ee] = f2bf(v * cc);
    }
    A[(long)m * 384 + 256 + e] =
        (e == ra || e == sa || e == pa) ? (unsigned short)0x3F80 : (unsigned short)0;
}

// ---------------- GEMM: C[M,1024] = A[M,384](bf16) @ Bw[1024,384]^T + bias ----
// EPI==0: store bf16 xg, GATE-INTERLEAVED: xg[row*1024 + (col&255)*4 + (col>>8)]
// EPI==1: sigmoid, store f32 remapped to [B,T,V].
template<int EPI>
__global__ __launch_bounds__(256) void k_gemm(
    const unsigned short* __restrict__ A,
    const float* __restrict__ Bw,
    const float* __restrict__ bias,
    unsigned short* __restrict__ obf,
    float* __restrict__ of) {
    __shared__ unsigned short As[128 * 32];
    __shared__ unsigned short Bs[128 * 32];
    const int m0 = blockIdx.x * 128, n0 = blockIdx.y * 128;
    const int tid = threadIdx.x;
    const int wave = tid >> 6, lane = tid & 63;
    const int wm = wave >> 1, wn = wave & 1;
    const int n = lane & 15, q = lane >> 4;
    f32x4 acc[4][4] = {};
    for (int ks = 0; ks < 12; ++ks) {
        __syncthreads();
        {
            int rr = tid >> 2, cc = (tid & 3) * 8;
            const unsigned short* g = A + (long)(m0 + rr) * 384 + ks * 32 + cc;
            uint4 v0 = *(const uint4*)g;
            uint4 v1 = *(const uint4*)(g + 64 * 384);
            *(uint4*)(&As[rr * 32 + cc]) = v0;
            *(uint4*)(&As[(rr + 64) * 32 + cc]) = v1;
        }
        {
            int rr = tid >> 3, cc = (tid & 7) * 4;
#pragma unroll
            for (int j = 0; j < 4; ++j) {
                int row = j * 32 + rr;
                float4 f = *(const float4*)(Bw + (long)(n0 + row) * 384 + ks * 32 + cc);
                ushort4 h;
                h.x = f2bf(f.x); h.y = f2bf(f.y); h.z = f2bf(f.z); h.w = f2bf(f.w);
                *(ushort4*)(&Bs[row * 32 + cc]) = h;
            }
        }
        __syncthreads();
        bf16x8 af[4], bfr[4];
#pragma unroll
        for (int mt = 0; mt < 4; ++mt)
            af[mt] = ld8(&As[(wm * 64 + mt * 16 + n) * 32 + q * 8]);
#pragma unroll
        for (int nt = 0; nt < 4; ++nt)
            bfr[nt] = ld8(&Bs[(wn * 64 + nt * 16 + n) * 32 + q * 8]);
#pragma unroll
        for (int mt = 0; mt < 4; ++mt)
#pragma unroll
            for (int nt = 0; nt < 4; ++nt)
                acc[mt][nt] = __builtin_amdgcn_mfma_f32_16x16x32_bf16(
                    af[mt], bfr[nt], acc[mt][nt], 0, 0, 0);
    }
#pragma unroll
    for (int mt = 0; mt < 4; ++mt) {
#pragma unroll
        for (int nt = 0; nt < 4; ++nt) {
            int col = n0 + wn * 64 + nt * 16 + n;
            float bv = bias[col];
#pragma unroll
            for (int rg = 0; rg < 4; ++rg) {
                int row = m0 + wm * 64 + mt * 16 + q * 4 + rg;
                float v = acc[mt][nt][rg] + bv;
                if (EPI == 0) {
                    obf[(long)row * 1024 + (col & 255) * 4 + (col >> 8)] = f2bf(v);
                } else {
                    int bb = row & 127, tt = row >> 7;
                    of[((long)bb * 200 + tt) * 1024 + col] = sigmoidf_(v);
                }
            }
        }
    }
}

// ---------------- LSTM: batch-split, NO inter-WG sync ------------------------
// 32 WGs x 4 batch rows x 4 waves. Wave owns 64 hidden units = 16 col-tiles.
// Register file = 512/lane/SIMD unified (arch<=256 + AGPR<=256). Split:
//   ub0,ub1 (8 tiles, 256 regs) -> AGPR (asm-forced)
//   ub2     (4 tiles, 128 regs) -> arch VGPR
//   ub3     (4 tiles)           -> LDS stream
// amdgpu_waves_per_eu(1,1): declare max occupancy 1 wave/EU so the register
// allocator budgets the FULL 512-reg file instead of spilling to stay <=256.
#define HB_STRIDE 288
__global__ __launch_bounds__(256)
__attribute__((amdgpu_waves_per_eu(1, 1)))
void k_lstm(
    const unsigned short* __restrict__ xg,   // [200*128][256][4] bf16 gate-interleaved
    const unsigned short* __restrict__ Wbf,  // [1024][256] bf16
    unsigned short* __restrict__ h_all) {    // [200*128][256] bf16
    __shared__ unsigned short wlds[4 * 4 * 8 * 512];  // 128KB frag-linear (ub=3)
    __shared__ unsigned short hb[2][4 * HB_STRIDE];   // h state double buffer

    const int tid = threadIdx.x;
    const int w = tid >> 6, lane = tid & 63;
    const int n = lane & 15, q = lane >> 4;
    const int b0 = blockIdx.x * 4;

    // ---- AGPR-resident weights: ub=0,1 (8 tiles = 256 AGPRs), direct VMEM->AGPR
    bf16x8 wa[2][4][8];
#pragma unroll
    for (int ub = 0; ub < 2; ++ub)
#pragma unroll
        for (int g = 0; g < 4; ++g) {
            const unsigned short* src = Wbf + (g * 256 + w * 64 + ub * 16 + n) * 256 + q * 8;
#pragma unroll
            for (int kk = 0; kk < 8; ++kk)
                asm volatile("global_load_dwordx4 %0, %1, off"
                             : "=a"(wa[ub][g][kk]) : "v"(src + kk * 32));
        }
    asm volatile("s_waitcnt vmcnt(0)" ::: "memory");
    __builtin_amdgcn_sched_barrier(0);

    // ---- arch-VGPR weights: ub=2 (4 tiles = 128 VGPRs)
    bf16x8 wv[4][8];
#pragma unroll
    for (int g = 0; g < 4; ++g) {
        const unsigned short* src = Wbf + (g * 256 + w * 64 + 2 * 16 + n) * 256 + q * 8;
#pragma unroll
        for (int kk = 0; kk < 8; ++kk) wv[g][kk] = ld8(src + kk * 32);
    }
    // ---- LDS weights: ub=3 (4 tiles), frag-linear
#pragma unroll
    for (int g = 0; g < 4; ++g) {
        const unsigned short* src = Wbf + (g * 256 + w * 64 + 3 * 16 + n) * 256 + q * 8;
#pragma unroll
        for (int kk = 0; kk < 8; ++kk)
            *(uint4*)(&wlds[((w * 4 + g) * 8 + kk) * 512 + lane * 8]) =
                *(const uint4*)(src + kk * 32);
    }
    for (int i = tid; i < 4 * HB_STRIDE; i += 256) { hb[0][i] = 0; hb[1][i] = 0; }

    const int u = w * 64 + q * 16 + n;   // this lane's hidden unit
    const unsigned short* xgp = xg + (long)b0 * 1024 + u * 4;   // += 131072 per t
    unsigned short* hap = h_all + (long)b0 * 256 + u;           // += 32768 per t

    float cs[4] = {0.f, 0.f, 0.f, 0.f};
    __syncthreads();

    for (int t = 0; t < 200; ++t) {
        const int cur = t & 1, nxt = cur ^ 1;

        // xg loads issued now, consumed after the MFMA phase (latency hidden)
        uint2 xv[4];
#pragma unroll
        for (int r = 0; r < 4; ++r) xv[r] = *(const uint2*)(xgp + r * 1024);
        xgp += 131072;

        // h fragments once per step (reused by all 4 ub groups)
        bf16x8 hf[8];
#pragma unroll
        for (int kk = 0; kk < 8; ++kk)
            hf[kk] = ld8(&hb[cur][(n & 3) * HB_STRIDE + kk * 32 + q * 8]);

        f32x4 vg[4] = {};

        // ---- ub=0,1: AGPR-resident (asm MFMA, B operand in AGPR)
#pragma unroll
        for (int ub = 0; ub < 2; ++ub) {
            f32x4 acc[4] = {};
#pragma unroll
            for (int kk = 0; kk < 8; ++kk)
#pragma unroll
                for (int g = 0; g < 4; ++g)
                    asm("v_mfma_f32_16x16x32_bf16 %0, %1, %2, %0"
                        : "+v"(acc[g]) : "v"(hf[kk]), "a"(wa[ub][g][kk]));
#pragma unroll
            for (int g = 0; g < 4; ++g) vg[g] = (q == ub) ? acc[g] : vg[g];
        }
        // ---- ub=2: arch-VGPR-resident (builtin)
        {
            f32x4 acc[4] = {};
#pragma unroll
            for (int kk = 0; kk < 8; ++kk)
#pragma unroll
                for (int g = 0; g < 4; ++g)
                    acc[g] = __builtin_amdgcn_mfma_f32_16x16x32_bf16(
                        hf[kk], wv[g][kk], acc[g], 0, 0, 0);
#pragma unroll
            for (int g = 0; g < 4; ++g) vg[g] = (q == 2) ? acc[g] : vg[g];
        }
        // ---- ub=3: LDS-streamed
        {
            f32x4 acc[4] = {};
#pragma unroll
            for (int kk = 0; kk < 8; ++kk) {
#pragma unroll
                for (int g = 0; g < 4; ++g) {
                    bf16x8 wf = ld8(&wlds[((w * 4 + g) * 8 + kk) * 512 + lane * 8]);
                    acc[g] = __builtin_amdgcn_mfma_f32_16x16x32_bf16(
                        hf[kk], wf, acc[g], 0, 0, 0);
                }
            }
#pragma unroll
            for (int g = 0; g < 4; ++g) vg[g] = (q == 3) ? acc[g] : vg[g];
        }

        // ---- elementwise LSTM update, 4 batch rows (acc row rg == batch row rg)
#pragma unroll
        for (int r = 0; r < 4; ++r) {
            float iv = vg[0][r] + bf2f((unsigned short)(xv[r].x & 0xFFFFu));
            float fv = vg[1][r] + bf2f((unsigned short)(xv[r].x >> 16));
            float gg = vg[2][r] + bf2f((unsigned short)(xv[r].y & 0xFFFFu));
            float ov = vg[3][r] + bf2f((unsigned short)(xv[r].y >> 16));
            float cn = sigmoidf_(fv) * cs[r] + sigmoidf_(iv) * tanhf_(gg);
            float hv = sigmoidf_(ov) * tanhf_(cn);
            cs[r] = cn;
            unsigned short hbv = f2bf(hv);
            hb[nxt][r * HB_STRIDE + u] = hbv;
            hap[r * 256] = hbv;
        }
        hap += 32768;
        __syncthreads();
    }
}

extern "C" void kernel_launch(void* const* d_in, const int* in_sizes, int n_in,
                              void* d_out, int out_size, void* d_ws, size_t ws_size,
                              hipStream_t stream) {
    const int* c        = (const int*)d_in[0];
    const int* r        = (const int*)d_in[1];
    const int* rgap     = (const int*)d_in[2];
    const int* sgap     = (const int*)d_in[3];
    const int* pcount   = (const int*)d_in[4];
    const int* s_rgap   = (const int*)d_in[5];
    const int* s_sgap   = (const int*)d_in[6];
    const int* s_pcount = (const int*)d_in[7];
    const float* E      = (const float*)d_in[8];
    const float* cemb_W = (const float*)d_in[9];
    const float* W_ih   = (const float*)d_in[10];
    const float* W_hh   = (const float*)d_in[11];
    const float* b_ih   = (const float*)d_in[12];
    const float* b_hh   = (const float*)d_in[13];
    const float* out_W  = (const float*)d_in[14];
    const float* out_b  = (const float*)d_in[15];

    char* ws = (char*)d_ws;
    float* cWT            = (float*)(ws);                       // 131072 B
    float* bsum           = (float*)(ws + 131072);              // 4096 B
    unsigned short* Wbf   = (unsigned short*)(ws + 135168);     // 524288 B
    unsigned short* h_all = (unsigned short*)(ws + 659456);     // 13107200 B
    unsigned short* Abuf  = (unsigned short*)(ws + 13766656);   // 19660800 B
    unsigned short* xg    = (unsigned short*)(ws + 33427456);   // 52428800 B

    k_prep<<<256, 256, 0, stream>>>(cemb_W, b_ih, b_hh, W_hh, cWT, bsum, Wbf);
    k_build_in<<<25600, 128, 0, stream>>>(c, r, rgap, sgap, pcount, E, cWT, Abuf);
    k_gemm<0><<<dim3(200, 8), 256, 0, stream>>>(Abuf, W_ih, bsum, xg, nullptr);
    k_lstm<<<32, 256, 0, stream>>>(xg, Wbf, h_all);
    k_build_out<<<25600, 128, 0, stream>>>(s_rgap, s_sgap, s_pcount, h_all, cWT, Abuf);
    k_gemm<1><<<dim3(200, 8), 256, 0, stream>>>(Abuf, out_W, out_b, nullptr, (float*)d_out);
}

// Round 8
// 476.996 us; speedup vs baseline: 1.2972x; 1.2972x over previous
//
#include <hip/hip_runtime.h>

typedef __bf16 bf16x8 __attribute__((ext_vector_type(8)));
typedef float f32x4 __attribute__((ext_vector_type(4)));

__device__ __forceinline__ unsigned short f2bf(float f) {
    union { float f; unsigned u; } v; v.f = f;
    unsigned u = v.u;
    return (unsigned short)((u + 0x7FFFu + ((u >> 16) & 1u)) >> 16);
}
__device__ __forceinline__ float bf2f(unsigned short h) {
    union { unsigned u; float f; } v; v.u = ((unsigned)h) << 16;
    return v.f;
}
__device__ __forceinline__ bf16x8 ld8(const unsigned short* p) {
    union { uint4 u; bf16x8 b; } cv;
    cv.u = *(const uint4*)p;
    return cv.b;
}
__device__ __forceinline__ float sigmoidf_(float x) {
    return __builtin_amdgcn_rcpf(1.0f + __expf(-x));
}
__device__ __forceinline__ float tanhf_(float x) {
    float xc = fminf(fmaxf(x, -15.0f), 15.0f);
    float e = __expf(-2.0f * xc);
    return (1.0f - e) * __builtin_amdgcn_rcpf(1.0f + e);
}

// ---------------- prep: transpose cemb_W, bias sum, W_hh -> fp8 e4m3 x16 -----
__global__ void k_prep(const float* __restrict__ cemb_W,
                       const float* __restrict__ b_ih, const float* __restrict__ b_hh,
                       const float* __restrict__ W_hh,
                       float* __restrict__ cWT, float* __restrict__ bsum,
                       unsigned char* __restrict__ Wq8) {
    int i = blockIdx.x * blockDim.x + threadIdx.x;
    int stride = gridDim.x * blockDim.x;
    const int TOT = 32768 + 1024 + 262144;
    for (; i < TOT; i += stride) {
        if (i < 32768) {
            int idx = i >> 8, e = i & 255;
            cWT[idx * 256 + e] = cemb_W[e * 128 + idx];   // cWT[i][e] = cemb_W[e][i]
        } else if (i < 33792) {
            int g = i - 32768;
            bsum[g] = b_ih[g] + b_hh[g];
        } else {
            int j = i - 33792;
            // scale x16 moves N(0,0.02) weights out of e4m3 subnormal floor
            unsigned p = __builtin_amdgcn_cvt_pk_fp8_f32(W_hh[j] * 16.0f, 0.0f, 0, false);
            Wq8[j] = (unsigned char)p;
        }
    }
}

// ---------------- build A_in = [xemb * Cct, onehots] (bf16, rows m = t*128+b) --
__global__ __launch_bounds__(128) void k_build_in(
    const int* __restrict__ c, const int* __restrict__ r,
    const int* __restrict__ rgap, const int* __restrict__ sgap, const int* __restrict__ pcount,
    const float* __restrict__ E, const float* __restrict__ cWT,
    unsigned short* __restrict__ A) {
    int m = blockIdx.x;
    int b = m & 127, t = m >> 7;
    int src = b * 200 + t;
    int x = c[src] + 1024 * r[src];
    int ra = rgap[src], sa = 32 + sgap[src], pa = 64 + pcount[src];
    int e = threadIdx.x;
#pragma unroll
    for (int j = 0; j < 2; ++j) {
        int ee = e + j * 128;
        float cc = cWT[ra * 256 + ee] + cWT[sa * 256 + ee] + cWT[pa * 256 + ee];
        A[(long)m * 384 + ee] = f2bf(E[(long)x * 256 + ee] * cc);
    }
    A[(long)m * 384 + 256 + e] =
        (e == ra || e == sa || e == pa) ? (unsigned short)0x3F80 : (unsigned short)0;
}

// ---------------- build A_out = [h * Cct_shft, onehots] ----------------------
__global__ __launch_bounds__(128) void k_build_out(
    const int* __restrict__ rgap, const int* __restrict__ sgap, const int* __restrict__ pcount,
    const unsigned short* __restrict__ h_all, const float* __restrict__ cWT,
    unsigned short* __restrict__ A) {
    int m = blockIdx.x;
    int b = m & 127, t = m >> 7;
    int src = b * 200 + t;
    int ra = rgap[src], sa = 32 + sgap[src], pa = 64 + pcount[src];
    int e = threadIdx.x;
#pragma unroll
    for (int j = 0; j < 2; ++j) {
        int ee = e + j * 128;
        float cc = cWT[ra * 256 + ee] + cWT[sa * 256 + ee] + cWT[pa * 256 + ee];
        float v = bf2f(h_all[(long)m * 256 + ee]);
        A[(long)m * 384 + ee] = f2bf(v * cc);
    }
    A[(long)m * 384 + 256 + e] =
        (e == ra || e == sa || e == pa) ? (unsigned short)0x3F80 : (unsigned short)0;
}

// ---------------- GEMM: C[M,1024] = A[M,384](bf16) @ Bw[1024,384]^T + bias ----
// EPI==0: store bf16 xg, GATE-INTERLEAVED: xg[row*1024 + (col&255)*4 + (col>>8)]
// EPI==1: sigmoid, store f32 remapped to [B,T,V].
template<int EPI>
__global__ __launch_bounds__(256) void k_gemm(
    const unsigned short* __restrict__ A,
    const float* __restrict__ Bw,
    const float* __restrict__ bias,
    unsigned short* __restrict__ obf,
    float* __restrict__ of) {
    __shared__ unsigned short As[128 * 32];
    __shared__ unsigned short Bs[128 * 32];
    const int m0 = blockIdx.x * 128, n0 = blockIdx.y * 128;
    const int tid = threadIdx.x;
    const int wave = tid >> 6, lane = tid & 63;
    const int wm = wave >> 1, wn = wave & 1;
    const int n = lane & 15, q = lane >> 4;
    f32x4 acc[4][4] = {};
    for (int ks = 0; ks < 12; ++ks) {
        __syncthreads();
        {
            int rr = tid >> 2, cc = (tid & 3) * 8;
            const unsigned short* g = A + (long)(m0 + rr) * 384 + ks * 32 + cc;
            uint4 v0 = *(const uint4*)g;
            uint4 v1 = *(const uint4*)(g + 64 * 384);
            *(uint4*)(&As[rr * 32 + cc]) = v0;
            *(uint4*)(&As[(rr + 64) * 32 + cc]) = v1;
        }
        {
            int rr = tid >> 3, cc = (tid & 7) * 4;
#pragma unroll
            for (int j = 0; j < 4; ++j) {
                int row = j * 32 + rr;
                float4 f = *(const float4*)(Bw + (long)(n0 + row) * 384 + ks * 32 + cc);
                ushort4 h;
                h.x = f2bf(f.x); h.y = f2bf(f.y); h.z = f2bf(f.z); h.w = f2bf(f.w);
                *(ushort4*)(&Bs[row * 32 + cc]) = h;
            }
        }
        __syncthreads();
        bf16x8 af[4], bfr[4];
#pragma unroll
        for (int mt = 0; mt < 4; ++mt)
            af[mt] = ld8(&As[(wm * 64 + mt * 16 + n) * 32 + q * 8]);
#pragma unroll
        for (int nt = 0; nt < 4; ++nt)
            bfr[nt] = ld8(&Bs[(wn * 64 + nt * 16 + n) * 32 + q * 8]);
#pragma unroll
        for (int mt = 0; mt < 4; ++mt)
#pragma unroll
            for (int nt = 0; nt < 4; ++nt)
                acc[mt][nt] = __builtin_amdgcn_mfma_f32_16x16x32_bf16(
                    af[mt], bfr[nt], acc[mt][nt], 0, 0, 0);
    }
#pragma unroll
    for (int mt = 0; mt < 4; ++mt) {
#pragma unroll
        for (int nt = 0; nt < 4; ++nt) {
            int col = n0 + wn * 64 + nt * 16 + n;
            float bv = bias[col];
#pragma unroll
            for (int rg = 0; rg < 4; ++rg) {
                int row = m0 + wm * 64 + mt * 16 + q * 4 + rg;
                float v = acc[mt][nt][rg] + bv;
                if (EPI == 0) {
                    obf[(long)row * 1024 + (col & 255) * 4 + (col >> 8)] = f2bf(v);
                } else {
                    int bb = row & 127, tt = row >> 7;
                    of[((long)bb * 200 + tt) * 1024 + col] = sigmoidf_(v);
                }
            }
        }
    }
}

// ---------------- LSTM: batch-split, NO inter-WG sync, FP8 weights -----------
// 32 WGs x 4 batch rows x 4 waves. Wave owns 64 hidden units = 16 col-tiles.
// fp8 e4m3 halves fragment size: ALL 16 tiles = 128 x i64 = 256 AGPRs exactly.
// No VGPR weights, no LDS weight streaming -> arch VGPR pressure ~130, no spill.
// W and h both pre-scaled x16 (out of e4m3 subnormal floor); acc * 1/256 undoes.
#define HB8_STRIDE 264
__global__ __launch_bounds__(256, 1) void k_lstm(
    const unsigned short* __restrict__ xg,   // [200*128][256][4] bf16 gate-interleaved
    const unsigned char* __restrict__ Wq8,   // [1024][256] fp8 e4m3 (x16)
    unsigned short* __restrict__ h_all) {    // [200*128][256] bf16
    __shared__ unsigned char hb8[2][4 * HB8_STRIDE];  // h state fp8, double buffer

    const int tid = threadIdx.x;
    const int w = tid >> 6, lane = tid & 63;
    const int n = lane & 15, q = lane >> 4;
    const int b0 = blockIdx.x * 4;

    // ---- ALL 16 weight tiles -> AGPR (exactly 256), direct VMEM->AGPR -------
    unsigned long wa[16][8];
#pragma unroll
    for (int ub = 0; ub < 4; ++ub)
#pragma unroll
        for (int g = 0; g < 4; ++g) {
            const unsigned char* src = Wq8 + ((g * 256 + w * 64 + ub * 16 + n) << 8) + q * 8;
#pragma unroll
            for (int kk = 0; kk < 8; ++kk)
                asm volatile("global_load_dwordx2 %0, %1, off"
                             : "=a"(wa[ub * 4 + g][kk]) : "v"(src + kk * 32));
        }
    asm volatile("s_waitcnt vmcnt(0)" ::: "memory");
    __builtin_amdgcn_sched_barrier(0);

    for (int i = tid; i < 4 * HB8_STRIDE; i += 256) { hb8[0][i] = 0; hb8[1][i] = 0; }

    const int u = w * 64 + q * 16 + n;   // this lane's hidden unit
    const unsigned short* xgp = xg + (long)b0 * 1024 + u * 4;   // += 131072 per t
    unsigned short* hap = h_all + (long)b0 * 256 + u;           // += 32768 per t

    float cs[4] = {0.f, 0.f, 0.f, 0.f};
    __syncthreads();

    const float S = 1.0f / 256.0f;  // undo x16 * x16 operand scaling (exact)

    for (int t = 0; t < 200; ++t) {
        const int cur = t & 1, nxt = cur ^ 1;

        // xg loads issued now, consumed after the MFMA phase (latency hidden)
        uint2 xv[4];
#pragma unroll
        for (int r = 0; r < 4; ++r) xv[r] = *(const uint2*)(xgp + r * 1024);
        xgp += 131072;

        // h fragments once per step: 8 x ds_read_b64 (fp8, rows replicated x4)
        unsigned long hf[8];
#pragma unroll
        for (int kk = 0; kk < 8; ++kk)
            hf[kk] = *(const unsigned long*)(&hb8[cur][(n & 3) * HB8_STRIDE + kk * 32 + q * 8]);

        f32x4 vg[4] = {};
#pragma unroll
        for (int ub = 0; ub < 4; ++ub) {
            f32x4 acc[4] = {};
#pragma unroll
            for (int kk = 0; kk < 8; ++kk)
#pragma unroll
                for (int g = 0; g < 4; ++g)
                    asm("v_mfma_f32_16x16x32_fp8_fp8 %0, %1, %2, %0"
                        : "+v"(acc[g]) : "v"(hf[kk]), "a"(wa[ub * 4 + g][kk]));
#pragma unroll
            for (int g = 0; g < 4; ++g) vg[g] = (q == ub) ? acc[g] : vg[g];
        }

        // ---- elementwise LSTM update, 4 batch rows (acc row rg == batch row rg)
#pragma unroll
        for (int r = 0; r < 4; ++r) {
            float iv = vg[0][r] * S + bf2f((unsigned short)(xv[r].x & 0xFFFFu));
            float fv = vg[1][r] * S + bf2f((unsigned short)(xv[r].x >> 16));
            float gg = vg[2][r] * S + bf2f((unsigned short)(xv[r].y & 0xFFFFu));
            float ov = vg[3][r] * S + bf2f((unsigned short)(xv[r].y >> 16));
            float cn = sigmoidf_(fv) * cs[r] + sigmoidf_(iv) * tanhf_(gg);
            float hv = sigmoidf_(ov) * tanhf_(cn);
            cs[r] = cn;
            hap[r * 256] = f2bf(hv);
            unsigned p8 = __builtin_amdgcn_cvt_pk_fp8_f32(hv * 16.0f, 0.0f, 0, false);
            hb8[nxt][r * HB8_STRIDE + u] = (unsigned char)p8;
        }
        hap += 32768;
        __syncthreads();
    }
}

extern "C" void kernel_launch(void* const* d_in, const int* in_sizes, int n_in,
                              void* d_out, int out_size, void* d_ws, size_t ws_size,
                              hipStream_t stream) {
    const int* c        = (const int*)d_in[0];
    const int* r        = (const int*)d_in[1];
    const int* rgap     = (const int*)d_in[2];
    const int* sgap     = (const int*)d_in[3];
    const int* pcount   = (const int*)d_in[4];
    const int* s_rgap   = (const int*)d_in[5];
    const int* s_sgap   = (const int*)d_in[6];
    const int* s_pcount = (const int*)d_in[7];
    const float* E      = (const float*)d_in[8];
    const float* cemb_W = (const float*)d_in[9];
    const float* W_ih   = (const float*)d_in[10];
    const float* W_hh   = (const float*)d_in[11];
    const float* b_ih   = (const float*)d_in[12];
    const float* b_hh   = (const float*)d_in[13];
    const float* out_W  = (const float*)d_in[14];
    const float* out_b  = (const float*)d_in[15];

    char* ws = (char*)d_ws;
    float* cWT            = (float*)(ws);                       // 131072 B
    float* bsum           = (float*)(ws + 131072);              // 4096 B
    unsigned char* Wq8    = (unsigned char*)(ws + 135168);      // 262144 B
    unsigned short* h_all = (unsigned short*)(ws + 397312);     // 13107200 B
    unsigned short* Abuf  = (unsigned short*)(ws + 13504512);   // 19660800 B
    unsigned short* xg    = (unsigned short*)(ws + 33165312);   // 52428800 B

    k_prep<<<256, 256, 0, stream>>>(cemb_W, b_ih, b_hh, W_hh, cWT, bsum, Wq8);
    k_build_in<<<25600, 128, 0, stream>>>(c, r, rgap, sgap, pcount, E, cWT, Abuf);
    k_gemm<0><<<dim3(200, 8), 256, 0, stream>>>(Abuf, W_ih, bsum, xg, nullptr);
    k_lstm<<<32, 256, 0, stream>>>(xg, Wq8, h_all);
    k_build_out<<<25600, 128, 0, stream>>>(s_rgap, s_sgap, s_pcount, h_all, cWT, Abuf);
    k_gemm<1><<<dim3(200, 8), 256, 0, stream>>>(Abuf, out_W, out_b, nullptr, (float*)d_out);
}

// Round 9
// 395.867 us; speedup vs baseline: 1.5630x; 1.2049x over previous
//
#include <hip/hip_runtime.h>

typedef __bf16 bf16x8 __attribute__((ext_vector_type(8)));
typedef float f32x4 __attribute__((ext_vector_type(4)));

__device__ __forceinline__ unsigned short f2bf(float f) {
    union { float f; unsigned u; } v; v.f = f;
    unsigned u = v.u;
    return (unsigned short)((u + 0x7FFFu + ((u >> 16) & 1u)) >> 16);
}
__device__ __forceinline__ float bf2f(unsigned short h) {
    union { unsigned u; float f; } v; v.u = ((unsigned)h) << 16;
    return v.f;
}
__device__ __forceinline__ bf16x8 ld8(const unsigned short* p) {
    union { uint4 u; bf16x8 b; } cv;
    cv.u = *(const uint4*)p;
    return cv.b;
}
__device__ __forceinline__ float sigmoidf_(float x) {
    return __builtin_amdgcn_rcpf(1.0f + __expf(-x));
}
__device__ __forceinline__ float tanhf_(float x) {
    float xc = fminf(fmaxf(x, -15.0f), 15.0f);
    float e = __expf(-2.0f * xc);
    return (1.0f - e) * __builtin_amdgcn_rcpf(1.0f + e);
}

// ---------------- prep: transpose cemb_W, bias sum, W_hh -> fp8 e4m3 x16 -----
__global__ void k_prep(const float* __restrict__ cemb_W,
                       const float* __restrict__ b_ih, const float* __restrict__ b_hh,
                       const float* __restrict__ W_hh,
                       float* __restrict__ cWT, float* __restrict__ bsum,
                       unsigned char* __restrict__ Wq8) {
    int i = blockIdx.x * blockDim.x + threadIdx.x;
    int stride = gridDim.x * blockDim.x;
    const int TOT = 32768 + 1024 + 262144;
    for (; i < TOT; i += stride) {
        if (i < 32768) {
            int idx = i >> 8, e = i & 255;
            cWT[idx * 256 + e] = cemb_W[e * 128 + idx];   // cWT[i][e] = cemb_W[e][i]
        } else if (i < 33792) {
            int g = i - 32768;
            bsum[g] = b_ih[g] + b_hh[g];
        } else {
            int j = i - 33792;
            // scale x16 moves N(0,0.02) weights out of e4m3 subnormal floor
            unsigned p = __builtin_amdgcn_cvt_pk_fp8_f32(W_hh[j] * 16.0f, 0.0f, 0, false);
            Wq8[j] = (unsigned char)p;
        }
    }
}

// ---------------- build A_in = [xemb * Cct, onehots] (bf16, rows m = t*128+b) --
__global__ __launch_bounds__(128) void k_build_in(
    const int* __restrict__ c, const int* __restrict__ r,
    const int* __restrict__ rgap, const int* __restrict__ sgap, const int* __restrict__ pcount,
    const float* __restrict__ E, const float* __restrict__ cWT,
    unsigned short* __restrict__ A) {
    int m = blockIdx.x;
    int b = m & 127, t = m >> 7;
    int src = b * 200 + t;
    int x = c[src] + 1024 * r[src];
    int ra = rgap[src], sa = 32 + sgap[src], pa = 64 + pcount[src];
    int e = threadIdx.x;
#pragma unroll
    for (int j = 0; j < 2; ++j) {
        int ee = e + j * 128;
        float cc = cWT[ra * 256 + ee] + cWT[sa * 256 + ee] + cWT[pa * 256 + ee];
        A[(long)m * 384 + ee] = f2bf(E[(long)x * 256 + ee] * cc);
    }
    A[(long)m * 384 + 256 + e] =
        (e == ra || e == sa || e == pa) ? (unsigned short)0x3F80 : (unsigned short)0;
}

// ---------------- build A_out = [h * Cct_shft, onehots] ----------------------
__global__ __launch_bounds__(128) void k_build_out(
    const int* __restrict__ rgap, const int* __restrict__ sgap, const int* __restrict__ pcount,
    const unsigned short* __restrict__ h_all, const float* __restrict__ cWT,
    unsigned short* __restrict__ A) {
    int m = blockIdx.x;
    int b = m & 127, t = m >> 7;
    int src = b * 200 + t;
    int ra = rgap[src], sa = 32 + sgap[src], pa = 64 + pcount[src];
    int e = threadIdx.x;
#pragma unroll
    for (int j = 0; j < 2; ++j) {
        int ee = e + j * 128;
        float cc = cWT[ra * 256 + ee] + cWT[sa * 256 + ee] + cWT[pa * 256 + ee];
        float v = bf2f(h_all[(long)m * 256 + ee]);
        A[(long)m * 384 + ee] = f2bf(v * cc);
    }
    A[(long)m * 384 + 256 + e] =
        (e == ra || e == sa || e == pa) ? (unsigned short)0x3F80 : (unsigned short)0;
}

// ---------------- GEMM: C[M,1024] = A[M,384](bf16) @ Bw[1024,384]^T + bias ----
// EPI==0: store bf16 xg, GATE-INTERLEAVED: xg[row*1024 + (col&255)*4 + (col>>8)]
// EPI==1: sigmoid, store f32 remapped to [B,T,V].
template<int EPI>
__global__ __launch_bounds__(256) void k_gemm(
    const unsigned short* __restrict__ A,
    const float* __restrict__ Bw,
    const float* __restrict__ bias,
    unsigned short* __restrict__ obf,
    float* __restrict__ of) {
    __shared__ unsigned short As[128 * 32];
    __shared__ unsigned short Bs[128 * 32];
    const int m0 = blockIdx.x * 128, n0 = blockIdx.y * 128;
    const int tid = threadIdx.x;
    const int wave = tid >> 6, lane = tid & 63;
    const int wm = wave >> 1, wn = wave & 1;
    const int n = lane & 15, q = lane >> 4;
    f32x4 acc[4][4] = {};
    for (int ks = 0; ks < 12; ++ks) {
        __syncthreads();
        {
            int rr = tid >> 2, cc = (tid & 3) * 8;
            const unsigned short* g = A + (long)(m0 + rr) * 384 + ks * 32 + cc;
            uint4 v0 = *(const uint4*)g;
            uint4 v1 = *(const uint4*)(g + 64 * 384);
            *(uint4*)(&As[rr * 32 + cc]) = v0;
            *(uint4*)(&As[(rr + 64) * 32 + cc]) = v1;
        }
        {
            int rr = tid >> 3, cc = (tid & 7) * 4;
#pragma unroll
            for (int j = 0; j < 4; ++j) {
                int row = j * 32 + rr;
                float4 f = *(const float4*)(Bw + (long)(n0 + row) * 384 + ks * 32 + cc);
                ushort4 h;
                h.x = f2bf(f.x); h.y = f2bf(f.y); h.z = f2bf(f.z); h.w = f2bf(f.w);
                *(ushort4*)(&Bs[row * 32 + cc]) = h;
            }
        }
        __syncthreads();
        bf16x8 af[4], bfr[4];
#pragma unroll
        for (int mt = 0; mt < 4; ++mt)
            af[mt] = ld8(&As[(wm * 64 + mt * 16 + n) * 32 + q * 8]);
#pragma unroll
        for (int nt = 0; nt < 4; ++nt)
            bfr[nt] = ld8(&Bs[(wn * 64 + nt * 16 + n) * 32 + q * 8]);
#pragma unroll
        for (int mt = 0; mt < 4; ++mt)
#pragma unroll
            for (int nt = 0; nt < 4; ++nt)
                acc[mt][nt] = __builtin_amdgcn_mfma_f32_16x16x32_bf16(
                    af[mt], bfr[nt], acc[mt][nt], 0, 0, 0);
    }
#pragma unroll
    for (int mt = 0; mt < 4; ++mt) {
#pragma unroll
        for (int nt = 0; nt < 4; ++nt) {
            int col = n0 + wn * 64 + nt * 16 + n;
            float bv = bias[col];
#pragma unroll
            for (int rg = 0; rg < 4; ++rg) {
                int row = m0 + wm * 64 + mt * 16 + q * 4 + rg;
                float v = acc[mt][nt][rg] + bv;
                if (EPI == 0) {
                    obf[(long)row * 1024 + (col & 255) * 4 + (col >> 8)] = f2bf(v);
                } else {
                    int bb = row & 127, tt = row >> 7;
                    of[((long)bb * 200 + tt) * 1024 + col] = sigmoidf_(v);
                }
            }
        }
    }
}

// ---------------- LSTM: 128 WGs x 1 batch row x 8 waves, 2 waves/SIMD --------
// Wave w owns 32 hidden units = 8 fp8 col-tiles = 128 AGPRs (asm-pinned).
// Arch VGPR ~100 -> <=256 total/wave -> 2 waves/SIMD co-resident: MFMA pipe
// occupancy of one wave hides the other's blocking latency (fix for R8's
// 51%-MfmaUtil wall at 1 wave/SIMD).
// Batch row replicated x16 in A-frag: fp8 A-fragment read (kk*32+q*8) is
// row-independent -> LDS broadcast; elementwise = 1 row/lane.
__global__ __launch_bounds__(512, 2) void k_lstm(
    const unsigned short* __restrict__ xg,   // [200*128][256][4] bf16 gate-interleaved
    const unsigned char* __restrict__ Wq8,   // [1024][256] fp8 e4m3 (x16)
    unsigned short* __restrict__ h_all) {    // [200*128][256] bf16
    __shared__ unsigned char hb8[2][264];    // h state fp8 (1 row), double buffer

    const int tid = threadIdx.x;
    const int w = tid >> 6, lane = tid & 63;
    const int n = lane & 15, q = lane >> 4;
    const int b0 = blockIdx.x;               // this WG's batch row
    const int ug = q & 1;                    // lane's unit-group within the wave

    // ---- 8 weight tiles -> AGPR (128), direct VMEM->AGPR --------------------
    // tile (tg = ug2*4+g): cols g*256 + w*32 + ug2*16 + n, k = kk*32 + q*8
    unsigned long wa[8][8];
#pragma unroll
    for (int ug2 = 0; ug2 < 2; ++ug2)
#pragma unroll
        for (int g = 0; g < 4; ++g) {
            const unsigned char* src = Wq8 + ((g * 256 + w * 32 + ug2 * 16 + n) << 8) + q * 8;
#pragma unroll
            for (int kk = 0; kk < 8; ++kk)
                asm volatile("global_load_dwordx2 %0, %1, off"
                             : "=a"(wa[ug2 * 4 + g][kk]) : "v"(src + kk * 32));
        }
    asm volatile("s_waitcnt vmcnt(0)" ::: "memory");
    __builtin_amdgcn_sched_barrier(0);

    for (int i = tid; i < 264; i += 512) { hb8[0][i] = 0; hb8[1][i] = 0; }

    const int u = w * 32 + ug * 16 + n;      // this lane's hidden unit
    const unsigned short* xgp = xg + (long)b0 * 1024 + u * 4;   // += 131072 per t
    unsigned short* hap = h_all + (long)b0 * 256 + u;           // += 32768 per t
    const bool writer = (q < 2);             // one writer per unit (q and q+2 alias)

    float cs = 0.f;
    __syncthreads();

    for (int t = 0; t < 200; ++t) {
        const int cur = t & 1, nxt = cur ^ 1;

        // xg load issued now, consumed after the MFMA phase (latency hidden)
        uint2 xv = *(const uint2*)xgp;
        xgp += 131072;

        // h fragment: row-independent (replicated rows) -> LDS broadcast reads
        unsigned long hf[8];
#pragma unroll
        for (int kk = 0; kk < 8; ++kk)
            hf[kk] = *(const unsigned long*)(&hb8[cur][kk * 32 + q * 8]);

        // gates for this wave's 32 units: 2 unit-groups x 4 gates x 8 k-slices
        f32x4 vg[4] = {};
#pragma unroll
        for (int ug2 = 0; ug2 < 2; ++ug2) {
            f32x4 acc[4] = {};
#pragma unroll
            for (int kk = 0; kk < 8; ++kk)
#pragma unroll
                for (int g = 0; g < 4; ++g)
                    asm("v_mfma_f32_16x16x32_fp8_fp8 %0, %1, %2, %0"
                        : "+v"(acc[g]) : "v"(hf[kk]), "a"(wa[ug2 * 4 + g][kk]));
#pragma unroll
            for (int g = 0; g < 4; ++g) vg[g] = (ug == ug2) ? acc[g] : vg[g];
        }

        // ---- elementwise LSTM update (1 row; all acc rows identical, use [0])
        const float S = 1.0f / 256.0f;  // undo x16 * x16 operand scaling (exact)
        {
            float iv = vg[0][0] * S + bf2f((unsigned short)(xv.x & 0xFFFFu));
            float fv = vg[1][0] * S + bf2f((unsigned short)(xv.x >> 16));
            float gg = vg[2][0] * S + bf2f((unsigned short)(xv.y & 0xFFFFu));
            float ov = vg[3][0] * S + bf2f((unsigned short)(xv.y >> 16));
            float cn = sigmoidf_(fv) * cs + sigmoidf_(iv) * tanhf_(gg);
            float hv = sigmoidf_(ov) * tanhf_(cn);
            cs = cn;
            if (writer) {
                hap[0] = f2bf(hv);
                unsigned p8 = __builtin_amdgcn_cvt_pk_fp8_f32(hv * 16.0f, 0.0f, 0, false);
                hb8[nxt][u] = (unsigned char)p8;
            }
        }
        hap += 32768;
        __syncthreads();
    }
}

extern "C" void kernel_launch(void* const* d_in, const int* in_sizes, int n_in,
                              void* d_out, int out_size, void* d_ws, size_t ws_size,
                              hipStream_t stream) {
    const int* c        = (const int*)d_in[0];
    const int* r        = (const int*)d_in[1];
    const int* rgap     = (const int*)d_in[2];
    const int* sgap     = (const int*)d_in[3];
    const int* pcount   = (const int*)d_in[4];
    const int* s_rgap   = (const int*)d_in[5];
    const int* s_sgap   = (const int*)d_in[6];
    const int* s_pcount = (const int*)d_in[7];
    const float* E      = (const float*)d_in[8];
    const float* cemb_W = (const float*)d_in[9];
    const float* W_ih   = (const float*)d_in[10];
    const float* W_hh   = (const float*)d_in[11];
    const float* b_ih   = (const float*)d_in[12];
    const float* b_hh   = (const float*)d_in[13];
    const float* out_W  = (const float*)d_in[14];
    const float* out_b  = (const float*)d_in[15];

    char* ws = (char*)d_ws;
    float* cWT            = (float*)(ws);                       // 131072 B
    float* bsum           = (float*)(ws + 131072);              // 4096 B
    unsigned char* Wq8    = (unsigned char*)(ws + 135168);      // 262144 B
    unsigned short* h_all = (unsigned short*)(ws + 397312);     // 13107200 B
    unsigned short* Abuf  = (unsigned short*)(ws + 13504512);   // 19660800 B
    unsigned short* xg    = (unsigned short*)(ws + 33165312);   // 52428800 B

    k_prep<<<256, 256, 0, stream>>>(cemb_W, b_ih, b_hh, W_hh, cWT, bsum, Wq8);
    k_build_in<<<25600, 128, 0, stream>>>(c, r, rgap, sgap, pcount, E, cWT, Abuf);
    k_gemm<0><<<dim3(200, 8), 256, 0, stream>>>(Abuf, W_ih, bsum, xg, nullptr);
    k_lstm<<<128, 512, 0, stream>>>(xg, Wq8, h_all);
    k_build_out<<<25600, 128, 0, stream>>>(s_rgap, s_sgap, s_pcount, h_all, cWT, Abuf);
    k_gemm<1><<<dim3(200, 8), 256, 0, stream>>>(Abuf, out_W, out_b, nullptr, (float*)d_out);
}